// Round 3
// baseline (16076.973 us; speedup 1.0000x reference)
//
#include <hip/hip_runtime.h>
#include <hip/hip_bf16.h>
#include <math.h>

typedef unsigned short u16;
typedef unsigned int   u32;

// ---- model dims ----
#define BSZ   64
#define TT    96
#define CCH   16
#define INDIM 16
#define HD    256
#define NHEAD 8
#define DHEAD 32
#define NCLS  4
#define LSEQ  100      // TT + NCLS
#define NLAY  4
#define EPSV  1e-5f
#define BSEQ  (BSZ*CCH)        // 1024 sequences
#define MTOK  (BSEQ*LSEQ)      // 102400 tokens
#define NCH   8                // pipeline chunks
#define SCH   (BSEQ/NCH)       // 128 sequences per chunk
#define RCH   (MTOK/NCH)       // 12800 rows per chunk

__device__ __forceinline__ float bf2f(u16 x){ return __uint_as_float(((u32)x)<<16); }
__device__ __forceinline__ u16 f2bf(float f){
    u32 u = __float_as_uint(f);
    u32 r = (u + 0x7fffu + ((u>>16)&1u)) >> 16;
    return (u16)r;
}
__device__ __forceinline__ float lo16(u32 r){ return __uint_as_float(r<<16); }
__device__ __forceinline__ float hi16(u32 r){ return __uint_as_float(r&0xffff0000u); }

// ---------------- embed: h = [x@Wfc^T+bfc ; cls] + pos, layout (bs*C, L, H), bf16 out ------------
__global__ __launch_bounds__(256)
void k_embed(const float* __restrict__ x, const float* __restrict__ Wfc,
             const float* __restrict__ bfc, const float* __restrict__ cls,
             const float* __restrict__ pos, u16* __restrict__ h)
{
    int bid = blockIdx.x;              // s*LSEQ + l
    int s = bid / LSEQ, l = bid - s*LSEQ;
    int n = s >> 4, c = s & 15;
    int hc = threadIdx.x;
    float v;
    if (l < TT) {
        const float* xr = x + (size_t)((n*TT + l)*CCH + c)*INDIM;
        const float* wr = Wfc + hc*INDIM;
        float acc = bfc[hc];
        #pragma unroll
        for (int i=0;i<INDIM;i++) acc += xr[i] * wr[i];
        v = acc;
    } else {
        v = cls[(size_t)((l-TT)*CCH + c)*HD + hc];
    }
    v += pos[(size_t)(l*CCH + c)*HD + hc];
    h[(size_t)bid*HD + hc] = f2bf(v);
}

// ---------------- graph constructor ----------------
__global__ __launch_bounds__(256)
void k_graph_m(const float* __restrict__ emb, const float* __restrict__ Wl,
               const float* __restrict__ bl, float* __restrict__ m)
{
    int r = blockIdx.x, o = threadIdx.x;
    __shared__ float e[HD];
    e[o] = emb[r*HD + o];
    __syncthreads();
    const float* w = Wl + (size_t)o*HD;
    float acc = bl[o];
    for (int k=0;k<HD;k++) acc += e[k]*w[k];
    m[r*HD + o] = tanhf(acc);
}

__global__ __launch_bounds__(256)
void k_graph_a(const float* __restrict__ m1, const float* __restrict__ m2,
               float* __restrict__ a)
{
    int t = threadIdx.x; int v = t >> 4, w = t & 15;
    __shared__ float adj[16][17];
    float s1=0.f, s2=0.f;
    for (int k=0;k<HD;k++){
        s1 += m1[v*HD+k]*m2[w*HD+k];
        s2 += m2[v*HD+k]*m1[w*HD+k];
    }
    float g = tanhf(s1 - s2); g = g > 0.f ? g : 0.f;
    adj[v][w] = g + (v==w ? 1.f : 0.f);
    __syncthreads();
    float rs = 0.f;
    #pragma unroll
    for (int j=0;j<16;j++) rs += adj[v][j];
    a[t] = adj[v][w] / rs;
}

// ------- GEMM: C[M,N](bf16) = A[M,K](bf16) @ W[N,K](f32)^T + bias(f32), opt ReLU -------
// BM=64, BN=64, BK=32, 256 threads, 4x4 micro-tile, fp32 accumulate
__global__ __launch_bounds__(256)
void k_gemm64(const u16* __restrict__ A, int lda,
              const float* __restrict__ W, const float* __restrict__ bias,
              u16* __restrict__ C, int ldc, int K, int relu)
{
    __shared__ float As[32][64];
    __shared__ float Ws[32][64];
    int t = threadIdx.x;
    int tx = t & 15, ty = t >> 4;         // n0 = tx*4, m0 = ty*4
    size_t mb = (size_t)blockIdx.x * 64;
    int nb = blockIdx.y * 64;
    int rw = t >> 2, k8 = (t & 3) << 3;   // tile loader: row, col8
    float acc[4][4] = {};
    for (int k0=0; k0<K; k0+=32){
        {
            uint4 raw = *(const uint4*)&A[(mb+rw)*(size_t)lda + k0 + k8];
            u32 rr[4] = {raw.x, raw.y, raw.z, raw.w};
            #pragma unroll
            for (int j=0;j<4;j++){
                As[k8+2*j+0][rw] = lo16(rr[j]);
                As[k8+2*j+1][rw] = hi16(rr[j]);
            }
        }
        {
            const float* wp = &W[(size_t)(nb+rw)*K + k0 + k8];
            float4 w0 = *(const float4*)wp;
            float4 w1 = *(const float4*)(wp+4);
            Ws[k8+0][rw]=w0.x; Ws[k8+1][rw]=w0.y; Ws[k8+2][rw]=w0.z; Ws[k8+3][rw]=w0.w;
            Ws[k8+4][rw]=w1.x; Ws[k8+5][rw]=w1.y; Ws[k8+6][rw]=w1.z; Ws[k8+7][rw]=w1.w;
        }
        __syncthreads();
        #pragma unroll
        for (int kk=0;kk<32;kk++){
            float4 a4 = ((const float4*)As[kk])[ty];
            float4 b4 = ((const float4*)Ws[kk])[tx];
            float av[4] = {a4.x,a4.y,a4.z,a4.w};
            float bv[4] = {b4.x,b4.y,b4.z,b4.w};
            #pragma unroll
            for (int i=0;i<4;i++)
                #pragma unroll
                for (int j=0;j<4;j++)
                    acc[i][j] += av[i]*bv[j];
        }
        __syncthreads();
    }
    float bb[4];
    #pragma unroll
    for (int j=0;j<4;j++) bb[j] = bias[nb + tx*4 + j];
    #pragma unroll
    for (int i=0;i<4;i++){
        float v[4];
        #pragma unroll
        for (int j=0;j<4;j++){
            float o = acc[i][j] + bb[j];
            if (relu) o = o > 0.f ? o : 0.f;
            v[j] = o;
        }
        ushort4 o4;
        o4.x = f2bf(v[0]); o4.y = f2bf(v[1]); o4.z = f2bf(v[2]); o4.w = f2bf(v[3]);
        *(ushort4*)&C[(mb + ty*4 + i)*(size_t)ldc + nb + tx*4] = o4;
    }
}

// ------- fused attention per (sequence, head); writes o into the q slot (bf16) -------
__global__ __launch_bounds__(256)
void k_attn(u16* __restrict__ qkv)
{
    int bid = blockIdx.x;
    int s = bid >> 3, hh = bid & 7;
    // LDS overlay: vs [0,3200) ; qs [3200,6400) ; ks [6400,9700) ; S [3200,13300)
    __shared__ float sm[13300];
    float* vs = sm;
    float* qs = sm + 3200;      // [100][32]
    float* ks = sm + 6400;      // [100][33]
    float* S  = sm + 3200;      // [100][101] overwrites qs/ks after score phase
    int t = threadIdx.x;
    size_t base = (size_t)s*LSEQ*768 + hh*32;
    for (int idx=t; idx<LSEQ*16; idx+=256){
        int i = idx >> 4, d2 = (idx & 15) << 1;
        size_t r = base + (size_t)i*768 + d2;
        u32 q2 = *(const u32*)&qkv[r];
        u32 k2 = *(const u32*)&qkv[r+256];
        u32 v2 = *(const u32*)&qkv[r+512];
        qs[i*32+d2]   = lo16(q2); qs[i*32+d2+1] = hi16(q2);
        ks[i*33+d2]   = lo16(k2); ks[i*33+d2+1] = hi16(k2);
        vs[i*32+d2]   = lo16(v2); vs[i*32+d2+1] = hi16(v2);
    }
    __syncthreads();
    const float scale = 0.17677669529663687f;  // 1/sqrt(32)
    float sreg[40];
    #pragma unroll
    for (int u=0;u<40;u++) sreg[u] = 0.f;
    #pragma unroll 1
    for (int u=0;u<40;u++){
        int e = t + (u<<8);
        if (e < LSEQ*LSEQ){
            int i = e/100, j = e - i*100;
            int jmax = (i < TT) ? i : (LSEQ-1);
            if (j <= jmax){
                float acc = 0.f;
                #pragma unroll
                for (int d=0;d<32;d++) acc += qs[i*32+d]*ks[j*33+d];
                sreg[u] = acc*scale;
            }
        }
    }
    __syncthreads();   // done reading qs/ks
    #pragma unroll 1
    for (int u=0;u<40;u++){
        int e = t + (u<<8);
        if (e < LSEQ*LSEQ){
            int i = e/100, j = e - i*100;
            S[i*101+j] = sreg[u];
        }
    }
    __syncthreads();
    if (t < LSEQ){
        int i = t;
        int jmax = (i < TT) ? i : (LSEQ-1);
        float mx = -1e30f;
        for (int j=0;j<=jmax;j++) mx = fmaxf(mx, S[i*101+j]);
        float sum = 0.f;
        for (int j=0;j<=jmax;j++){ float ev = __expf(S[i*101+j]-mx); S[i*101+j]=ev; sum+=ev; }
        float inv = 1.f/sum;
        for (int j=0;j<=jmax;j++) S[i*101+j] *= inv;
        for (int j=jmax+1;j<LSEQ;j++) S[i*101+j] = 0.f;
    }
    __syncthreads();
    for (int idx=t; idx<LSEQ*16; idx+=256){
        int i = idx >> 4, d2 = (idx & 15) << 1;
        float a0 = 0.f, a1 = 0.f;
        for (int j=0;j<LSEQ;j++){
            float p = S[i*101+j];
            a0 += p*vs[j*32+d2];
            a1 += p*vs[j*32+d2+1];
        }
        u32 pk = (u32)f2bf(a0) | ((u32)f2bf(a1) << 16);
        *(u32*)&qkv[base + (size_t)i*768 + d2] = pk;
    }
}

// ------- fused GEMM(N=256) + bias + residual + LayerNorm, in-place h (bf16) -------
// BM=16, BN=256, BK=32; 256 threads; wave ty owns rows ty*4..ty*4+3 fully
__global__ __launch_bounds__(256)
void k_gemm_ln(const u16* __restrict__ A, int lda, int K,
               const float* __restrict__ W, const float* __restrict__ bias,
               u16* __restrict__ h, const float* __restrict__ gam,
               const float* __restrict__ bet, size_t row0)
{
    __shared__ float As[32][16];
    __shared__ float Ws[32][256];
    int t = threadIdx.x;
    int tx = t & 63, ty = t >> 6;
    size_t lr0 = (size_t)blockIdx.x * 16;       // local rows into A
    size_t gr0 = row0 + lr0;                    // global rows into h
    float acc[4][4] = {};
    for (int k0=0;k0<K;k0+=32){
        {
            int m = t >> 4, k = (t & 15) << 1;
            u32 raw = *(const u32*)&A[(lr0+m)*(size_t)lda + k0 + k];
            As[k][m] = lo16(raw); As[k+1][m] = hi16(raw);
        }
        #pragma unroll
        for (int j=0;j<4;j++){
            int idx8 = t + j*256;
            int nn = idx8 >> 2, k8 = (idx8 & 3) << 3;
            const float* wp = &W[(size_t)nn*K + k0 + k8];
            float4 w0 = *(const float4*)wp;
            float4 w1 = *(const float4*)(wp+4);
            Ws[k8+0][nn]=w0.x; Ws[k8+1][nn]=w0.y; Ws[k8+2][nn]=w0.z; Ws[k8+3][nn]=w0.w;
            Ws[k8+4][nn]=w1.x; Ws[k8+5][nn]=w1.y; Ws[k8+6][nn]=w1.z; Ws[k8+7][nn]=w1.w;
        }
        __syncthreads();
        #pragma unroll
        for (int kk=0;kk<32;kk++){
            float4 a4 = ((const float4*)As[kk])[ty];
            float4 b4 = ((const float4*)Ws[kk])[tx];
            float av[4] = {a4.x,a4.y,a4.z,a4.w};
            float bv[4] = {b4.x,b4.y,b4.z,b4.w};
            #pragma unroll
            for (int i=0;i<4;i++)
                #pragma unroll
                for (int j=0;j<4;j++)
                    acc[i][j] += av[i]*bv[j];
        }
        __syncthreads();
    }
    float g4[4], b4[4], bi4[4];
    #pragma unroll
    for (int j=0;j<4;j++){
        int nn = tx*4 + j;
        bi4[j] = bias[nn];
        g4[j]  = gam[nn];
        b4[j]  = bet[nn];
    }
    #pragma unroll
    for (int i=0;i<4;i++){
        size_t r = gr0 + ty*4 + i;
        ushort4 res = *(const ushort4*)&h[r*HD + tx*4];
        float v0 = acc[i][0]+bi4[0]+bf2f(res.x);
        float v1 = acc[i][1]+bi4[1]+bf2f(res.y);
        float v2 = acc[i][2]+bi4[2]+bf2f(res.z);
        float v3 = acc[i][3]+bi4[3]+bf2f(res.w);
        float s = v0+v1+v2+v3;
        #pragma unroll
        for (int m=1;m<64;m<<=1) s += __shfl_xor(s, m, 64);
        float mean = s * (1.f/256.f);
        float d0=v0-mean, d1=v1-mean, d2=v2-mean, d3=v3-mean;
        float vv = d0*d0+d1*d1+d2*d2+d3*d3;
        #pragma unroll
        for (int m=1;m<64;m<<=1) vv += __shfl_xor(vv, m, 64);
        float inv = rsqrtf(vv*(1.f/256.f) + EPSV);
        ushort4 o4;
        o4.x = f2bf(d0*inv*g4[0] + b4[0]);
        o4.y = f2bf(d1*inv*g4[1] + b4[1]);
        o4.z = f2bf(d2*inv*g4[2] + b4[2]);
        o4.w = f2bf(d3*inv*g4[3] + b4[3]);
        *(ushort4*)&h[r*HD + tx*4] = o4;
    }
}

// ---------------- mixprop on cls tokens, in-place h (bf16) update ----------------
__global__ __launch_bounds__(256)
void k_mixprop(u16* __restrict__ h, const float* __restrict__ a,
               const float* __restrict__ Wm, const float* __restrict__ bm)
{
    int n = blockIdx.x >> 2, tt = blockIdx.x & 3;
    __shared__ float xs[256][17], h1s[256][17], h2s[256][17];
    __shared__ float as[16][17];
    int t = threadIdx.x;
    as[t>>4][t&15] = a[t];
    for (int idx=t; idx<4096; idx+=256){
        int w = idx >> 8, hc = idx & 255;
        xs[hc][w] = bf2f(h[((size_t)(n*16 + w)*LSEQ + TT + tt)*HD + hc]);
    }
    __syncthreads();
    for (int idx=t; idx<4096; idx+=256){
        int v = idx & 15, hc = idx >> 4;
        float acc = 0.f;
        #pragma unroll
        for (int w=0;w<16;w++) acc += as[v][w]*xs[hc][w];
        h1s[hc][v] = acc;
    }
    __syncthreads();
    for (int idx=t; idx<4096; idx+=256){
        int v = idx & 15, hc = idx >> 4;
        float acc = 0.f;
        #pragma unroll
        for (int w=0;w<16;w++) acc += as[v][w]*h1s[hc][w];
        h2s[hc][v] = acc;
    }
    __syncthreads();
    int o = t;
    const float* wr = Wm + (size_t)o*768;
    float acc[16];
    #pragma unroll
    for (int w=0;w<16;w++) acc[w] = 0.f;
    for (int hc=0; hc<256; hc++){
        float w0 = wr[hc];
        float w1 = wr[256+hc];
        float w2 = wr[512+hc];
        #pragma unroll
        for (int w=0;w<16;w++)
            acc[w] += xs[hc][w]*w0 + h1s[hc][w]*w1 + h2s[hc][w]*w2;
    }
    float bb = bm[o];
    #pragma unroll
    for (int w=0;w<16;w++)
        h[((size_t)(n*16 + w)*LSEQ + TT + tt)*HD + o] = f2bf(acc[w] + bb);
}

// ---------------- head ----------------
__global__ __launch_bounds__(256)
void k_z(const u16* __restrict__ h, float* __restrict__ z)
{
    int bid = blockIdx.x, t = threadIdx.x;     // bid = n*16+c
    #pragma unroll
    for (int tc=0;tc<4;tc++)
        z[((size_t)bid*4 + tc)*HD + t] = tanhf(bf2f(h[((size_t)bid*LSEQ + TT + tc)*HD + t]));
}

__global__ __launch_bounds__(256)
void k_head1(const float* __restrict__ z, const float* __restrict__ Wd1,
             const float* __restrict__ bd1, float* __restrict__ d1)
{
    __shared__ float zch[64][129];
    __shared__ float wt[16][129];
    int t = threadIdx.x;
    int ol = t & 15, nq = t >> 4;
    int ob = blockIdx.x * 16;
    float acc[4] = {0.f,0.f,0.f,0.f};
    for (int kc=0; kc<16384; kc+=128){
        #pragma unroll 4
        for (int j=0;j<32;j++){
            int idx = t + j*256;
            int n = idx >> 7, k = idx & 127;
            zch[n][k] = z[(size_t)n*16384 + kc + k];
        }
        #pragma unroll
        for (int j=0;j<8;j++){
            int idx = t + j*256;
            int r = idx >> 7, k = idx & 127;
            wt[r][k] = Wd1[(size_t)(ob + r)*16384 + kc + k];
        }
        __syncthreads();
        for (int k=0;k<128;k++){
            float wv = wt[ol][k];
            #pragma unroll
            for (int u=0;u<4;u++) acc[u] += zch[nq + 16*u][k]*wv;
        }
        __syncthreads();
    }
    float bb = bd1[ob + ol];
    #pragma unroll
    for (int u=0;u<4;u++){
        float xx = acc[u] + bb;
        float ge = 0.5f*xx*(1.f + erff(xx*0.70710678118654752f));
        d1[(size_t)(nq + 16*u)*HD + ob + ol] = ge;
    }
}

__global__ __launch_bounds__(64)
void k_head2(const float* __restrict__ d1, const float* __restrict__ Wd2,
             const float* __restrict__ bd2, float* __restrict__ out)
{
    int n = blockIdx.x, lane = threadIdx.x;
    float p = 0.f;
    #pragma unroll
    for (int j=0;j<4;j++){
        int k = lane*4 + j;
        p += d1[(size_t)n*HD + k]*Wd2[k];
    }
    #pragma unroll
    for (int m=1;m<64;m<<=1) p += __shfl_xor(p, m, 64);
    if (lane==0) out[n] = p + bd2[0];
}

// ---------------- launch ----------------
extern "C" void kernel_launch(void* const* d_in, const int* in_sizes, int n_in,
                              void* d_out, int out_size, void* d_ws, size_t ws_size,
                              hipStream_t stream)
{
    const float* x    = (const float*)d_in[0];
    const float* Wfc  = (const float*)d_in[3];
    const float* bfc  = (const float*)d_in[4];
    const float* cls  = (const float*)d_in[5];
    const float* pos  = (const float*)d_in[6];
    const float* emb1 = (const float*)d_in[7];
    const float* emb2 = (const float*)d_in[8];
    const float* Wl1  = (const float*)d_in[9];
    const float* bl1  = (const float*)d_in[10];
    const float* Wl2  = (const float*)d_in[11];
    const float* bl2  = (const float*)d_in[12];
    const float* Wqkv = (const float*)d_in[13];
    const float* bqkv = (const float*)d_in[14];
    const float* Wo   = (const float*)d_in[15];
    const float* bo   = (const float*)d_in[16];
    const float* W1   = (const float*)d_in[17];
    const float* b1   = (const float*)d_in[18];
    const float* W2   = (const float*)d_in[19];
    const float* b2   = (const float*)d_in[20];
    const float* ln1g = (const float*)d_in[21];
    const float* ln1b = (const float*)d_in[22];
    const float* ln2g = (const float*)d_in[23];
    const float* ln2b = (const float*)d_in[24];
    const float* Wmlp = (const float*)d_in[25];
    const float* bmlp = (const float*)d_in[26];
    const float* Wd1  = (const float*)d_in[27];
    const float* bd1  = (const float*)d_in[28];
    const float* Wd2  = (const float*)d_in[29];
    const float* bd2  = (const float*)d_in[30];

    // workspace layout (bf16 intermediates): total ~83 MB
    u16* h   = (u16*)d_ws;                     // MTOK*HD        = 26,214,400 u16 (52.4 MB)
    u16* buf = h + (size_t)MTOK*HD;            // RCH*1024       = 13,107,200 u16 (26.2 MB)
    float* fs = (float*)(buf + (size_t)RCH*1024);
    float* m1 = fs;                            // 4096
    float* m2 = m1 + CCH*HD;                   // 4096
    float* an = m2 + CCH*HD;                   // 256
    float* z  = an + CCH*CCH;                  // 1,048,576 f32 (4.2 MB)
    float* d1 = z + (size_t)BSZ*CCH*NCLS*HD;   // 16,384 f32

    k_embed<<<MTOK, 256, 0, stream>>>(x, Wfc, bfc, cls, pos, h);
    k_graph_m<<<16, 256, 0, stream>>>(emb1, Wl1, bl1, m1);
    k_graph_m<<<16, 256, 0, stream>>>(emb2, Wl2, bl2, m2);
    k_graph_a<<<1, 256, 0, stream>>>(m1, m2, an);

    for (int l=0; l<NLAY; l++){
        if (l > 0)
            k_mixprop<<<BSZ*NCLS, 256, 0, stream>>>(h, an,
                Wmlp + (size_t)(l-1)*HD*768, bmlp + (size_t)(l-1)*HD);
        // attention pipeline, chunked over sequence groups
        for (int c=0; c<NCH; c++){
            size_t row0 = (size_t)c * RCH;
            k_gemm64<<<dim3(RCH/64, 768/64), 256, 0, stream>>>(
                h + row0*HD, HD, Wqkv + (size_t)l*768*HD, bqkv + (size_t)l*768,
                buf, 768, HD, 0);
            k_attn<<<SCH*NHEAD, 256, 0, stream>>>(buf);
            k_gemm_ln<<<RCH/16, 256, 0, stream>>>(
                buf, 768, HD, Wo + (size_t)l*HD*HD, bo + (size_t)l*HD,
                h, ln1g + (size_t)l*HD, ln1b + (size_t)l*HD, row0);
        }
        // feed-forward, chunked
        for (int c=0; c<NCH; c++){
            size_t row0 = (size_t)c * RCH;
            k_gemm64<<<dim3(RCH/64, 1024/64), 256, 0, stream>>>(
                h + row0*HD, HD, W1 + (size_t)l*1024*HD, b1 + (size_t)l*1024,
                buf, 1024, HD, 1);
            k_gemm_ln<<<RCH/16, 256, 0, stream>>>(
                buf, 1024, 1024, W2 + (size_t)l*HD*1024, b2 + (size_t)l*HD,
                h, ln2g + (size_t)l*HD, ln2b + (size_t)l*HD, row0);
        }
    }

    k_z<<<BSZ*CCH, 256, 0, stream>>>(h, z);
    k_head1<<<16, 256, 0, stream>>>(z, Wd1, bd1, d1);
    k_head2<<<BSZ, 64, 0, stream>>>(d1, Wd2, bd2, (float*)d_out);
}

// Round 4
// 5227.373 us; speedup vs baseline: 3.0755x; 3.0755x over previous
//
#include <hip/hip_runtime.h>
#include <hip/hip_bf16.h>
#include <math.h>

typedef unsigned short u16;
typedef unsigned int   u32;
typedef __attribute__((ext_vector_type(8))) short short8;   // 8 bf16 = 4 VGPRs
typedef __attribute__((ext_vector_type(4))) float f32x4;

// ---- model dims ----
#define BSZ   64
#define TT    96
#define CCH   16
#define INDIM 16
#define HD    256
#define NHEAD 8
#define DHEAD 32
#define NCLS  4
#define LSEQ  100      // TT + NCLS
#define NLAY  4
#define EPSV  1e-5f
#define BSEQ  (BSZ*CCH)        // 1024 sequences
#define MTOK  (BSEQ*LSEQ)      // 102400 tokens
#define NCH   8                // pipeline chunks
#define SCH   (BSEQ/NCH)       // 128 sequences per chunk
#define RCH   (MTOK/NCH)       // 12800 rows per chunk

__device__ __forceinline__ float bf2f(u16 x){ return __uint_as_float(((u32)x)<<16); }
__device__ __forceinline__ u16 f2bf(float f){
    u32 u = __float_as_uint(f);
    u32 r = (u + 0x7fffu + ((u>>16)&1u)) >> 16;
    return (u16)r;
}
__device__ __forceinline__ float lo16(u32 r){ return __uint_as_float(r<<16); }
__device__ __forceinline__ float hi16(u32 r){ return __uint_as_float(r&0xffff0000u); }

// ---------------- f32 -> bf16 bulk convert ----------------
__global__ __launch_bounds__(256)
void k_cvt(const float* __restrict__ src, u16* __restrict__ dst, int n)
{
    for (int i = blockIdx.x*256 + threadIdx.x; i < n; i += gridDim.x*256)
        dst[i] = f2bf(src[i]);
}

// ---------------- embed: h = [x@Wfc^T+bfc ; cls] + pos, layout (bs*C, L, H), bf16 out ----------
__global__ __launch_bounds__(256)
void k_embed(const float* __restrict__ x, const float* __restrict__ Wfc,
             const float* __restrict__ bfc, const float* __restrict__ cls,
             const float* __restrict__ pos, u16* __restrict__ h)
{
    int bid = blockIdx.x;              // s*LSEQ + l
    int s = bid / LSEQ, l = bid - s*LSEQ;
    int n = s >> 4, c = s & 15;
    int hc = threadIdx.x;
    float v;
    if (l < TT) {
        const float* xr = x + (size_t)((n*TT + l)*CCH + c)*INDIM;
        const float* wr = Wfc + hc*INDIM;
        float acc = bfc[hc];
        #pragma unroll
        for (int i=0;i<INDIM;i++) acc += xr[i] * wr[i];
        v = acc;
    } else {
        v = cls[(size_t)((l-TT)*CCH + c)*HD + hc];
    }
    v += pos[(size_t)(l*CCH + c)*HD + hc];
    h[(size_t)bid*HD + hc] = f2bf(v);
}

// ---------------- graph constructor ----------------
__global__ __launch_bounds__(256)
void k_graph_m(const float* __restrict__ emb, const float* __restrict__ Wl,
               const float* __restrict__ bl, float* __restrict__ m)
{
    int r = blockIdx.x, o = threadIdx.x;
    __shared__ float e[HD];
    e[o] = emb[r*HD + o];
    __syncthreads();
    const float* w = Wl + (size_t)o*HD;
    float acc = bl[o];
    for (int k=0;k<HD;k++) acc += e[k]*w[k];
    m[r*HD + o] = tanhf(acc);
}

__global__ __launch_bounds__(256)
void k_graph_a(const float* __restrict__ m1, const float* __restrict__ m2,
               float* __restrict__ a)
{
    int t = threadIdx.x; int v = t >> 4, w = t & 15;
    __shared__ float adj[16][17];
    float s1=0.f, s2=0.f;
    for (int k=0;k<HD;k++){
        s1 += m1[v*HD+k]*m2[w*HD+k];
        s2 += m2[v*HD+k]*m1[w*HD+k];
    }
    float g = tanhf(s1 - s2); g = g > 0.f ? g : 0.f;
    adj[v][w] = g + (v==w ? 1.f : 0.f);
    __syncthreads();
    float rs = 0.f;
    #pragma unroll
    for (int j=0;j<16;j++) rs += adj[v][j];
    a[t] = adj[v][w] / rs;
}

// ---------------- MFMA GEMM: C[M,N](bf16) = A[M,K](bf16) @ W[N,K](bf16)^T + bias(f32) ----------
// BM=128, BN=128, BK=32; 256 threads = 4 waves; each wave does 64x64 via 4x4 MFMA 16x16x32 tiles.
// LDS rows padded to 40 elements (80B = 20 banks) -> <=2-way conflicts (free).
__global__ __launch_bounds__(256)
void k_gemmA(const u16* __restrict__ A, int lda,
             const u16* __restrict__ W, const float* __restrict__ bias,
             u16* __restrict__ C, int ldc, int K, int relu)
{
    __shared__ u16 As[128*40];
    __shared__ u16 Ws[128*40];
    int t = threadIdx.x;
    int lane = t & 63, w = t >> 6;
    int wm = (w & 1)*64, wn = (w >> 1)*64;
    int fr = lane & 15, quad = lane >> 4;
    size_t mb = (size_t)blockIdx.x * 128;
    int nb = blockIdx.y * 128;
    int lrow = t >> 2, lch = (t & 3) << 3;     // loader: row(0..63), 8-elem chunk

    f32x4 acc[4][4] = {};
    for (int k0 = 0; k0 < K; k0 += 32){
        uint4 av0 = *(const uint4*)&A[(mb + lrow     )*(size_t)lda + k0 + lch];
        uint4 av1 = *(const uint4*)&A[(mb + lrow + 64)*(size_t)lda + k0 + lch];
        uint4 wv0 = *(const uint4*)&W[(size_t)(nb + lrow     )*K + k0 + lch];
        uint4 wv1 = *(const uint4*)&W[(size_t)(nb + lrow + 64)*K + k0 + lch];
        __syncthreads();   // previous compute done before overwriting LDS
        *(uint4*)&As[ lrow      *40 + lch] = av0;
        *(uint4*)&As[(lrow + 64)*40 + lch] = av1;
        *(uint4*)&Ws[ lrow      *40 + lch] = wv0;
        *(uint4*)&Ws[(lrow + 64)*40 + lch] = wv1;
        __syncthreads();
        short8 af[4], bf[4];
        #pragma unroll
        for (int mt=0; mt<4; mt++)
            af[mt] = *(const short8*)&As[(wm + mt*16 + fr)*40 + quad*8];
        #pragma unroll
        for (int nt=0; nt<4; nt++)
            bf[nt] = *(const short8*)&Ws[(wn + nt*16 + fr)*40 + quad*8];
        #pragma unroll
        for (int mt=0; mt<4; mt++)
            #pragma unroll
            for (int nt=0; nt<4; nt++)
                acc[mt][nt] = __builtin_amdgcn_mfma_f32_16x16x32_bf16(
                    af[mt], bf[nt], acc[mt][nt], 0, 0, 0);
    }
    float bb[4];
    #pragma unroll
    for (int nt=0; nt<4; nt++) bb[nt] = bias[nb + wn + nt*16 + fr];
    #pragma unroll
    for (int mt=0; mt<4; mt++){
        #pragma unroll
        for (int nt=0; nt<4; nt++){
            #pragma unroll
            for (int r=0; r<4; r++){
                float v = acc[mt][nt][r] + bb[nt];
                if (relu) v = v > 0.f ? v : 0.f;
                size_t rg = mb + wm + mt*16 + quad*4 + r;
                C[rg*(size_t)ldc + nb + wn + nt*16 + fr] = f2bf(v);
            }
        }
    }
}

// ---------------- attention: thread-per-query-row, online softmax, o -> q slot ----------------
// block = 256 threads = 2 (seq,head) pairs of 128 threads; K/V staged fp32 in LDS.
__global__ __launch_bounds__(256)
void k_attn(u16* __restrict__ qkv)
{
    __shared__ float kf[2][3200];
    __shared__ float vf[2][3200];
    int t = threadIdx.x;
    int p = t >> 7, t2 = t & 127;
    int gp = blockIdx.x*2 + p;
    int s = gp >> 3, hh = gp & 7;
    size_t base = (size_t)s*LSEQ*768 + hh*32;
    for (int idx=t2; idx<1600; idx+=128){
        int i = idx >> 4, d2 = (idx & 15) << 1;
        u32 kk = *(const u32*)&qkv[base + (size_t)i*768 + 256 + d2];
        u32 vv = *(const u32*)&qkv[base + (size_t)i*768 + 512 + d2];
        kf[p][i*32+d2]   = lo16(kk); kf[p][i*32+d2+1] = hi16(kk);
        vf[p][i*32+d2]   = lo16(vv); vf[p][i*32+d2+1] = hi16(vv);
    }
    const float scale = 0.17677669529663687f;  // 1/sqrt(32)
    float q[32];
    int i = t2;
    if (i < LSEQ){
        const u16* qp = &qkv[base + (size_t)i*768];
        #pragma unroll
        for (int c=0;c<4;c++){
            uint4 r4 = *(const uint4*)&qp[c*8];
            u32 rr[4] = {r4.x, r4.y, r4.z, r4.w};
            #pragma unroll
            for (int j=0;j<4;j++){
                q[c*8+2*j]   = lo16(rr[j])*scale;
                q[c*8+2*j+1] = hi16(rr[j])*scale;
            }
        }
    }
    __syncthreads();
    if (i < LSEQ){
        float m = -1e30f, l = 0.f, o[32];
        #pragma unroll
        for (int d=0;d<32;d++) o[d] = 0.f;
        int jmax = (i < TT) ? i : (LSEQ-1);
        for (int j=0; j<=jmax; j++){
            const float4* kr = (const float4*)&kf[p][j*32];
            float sc = 0.f;
            #pragma unroll
            for (int c=0;c<8;c++){
                float4 kk = kr[c];
                sc += q[4*c]*kk.x + q[4*c+1]*kk.y + q[4*c+2]*kk.z + q[4*c+3]*kk.w;
            }
            float mn = fmaxf(m, sc);
            float al = __expf(m - mn);
            float pj = __expf(sc - mn);
            l = l*al + pj;
            const float4* vr = (const float4*)&vf[p][j*32];
            #pragma unroll
            for (int c=0;c<8;c++){
                float4 vv = vr[c];
                o[4*c]   = o[4*c]*al   + pj*vv.x;
                o[4*c+1] = o[4*c+1]*al + pj*vv.y;
                o[4*c+2] = o[4*c+2]*al + pj*vv.z;
                o[4*c+3] = o[4*c+3]*al + pj*vv.w;
            }
            m = mn;
        }
        float inv = 1.f/l;
        #pragma unroll
        for (int d2=0; d2<32; d2+=2){
            u32 pk = (u32)f2bf(o[d2]*inv) | ((u32)f2bf(o[d2+1]*inv) << 16);
            *(u32*)&qkv[base + (size_t)i*768 + d2] = pk;
        }
    }
}

// ---------------- residual + LayerNorm: h[row] = LN(g[row_local] + h[row]) ----------------
// block = 256 threads = 8 rows x 32 lanes x 8 cols
__global__ __launch_bounds__(256)
void k_ln(const u16* __restrict__ g, u16* __restrict__ h,
          const float* __restrict__ gam, const float* __restrict__ bet,
          size_t row0)
{
    int t = threadIdx.x;
    int rl = t >> 5, lane32 = t & 31, c8 = lane32 << 3;
    size_t lrow = (size_t)blockIdx.x*8 + rl;
    size_t grow = row0 + lrow;
    uint4 g4 = *(const uint4*)&g[lrow*HD + c8];
    uint4 h4 = *(const uint4*)&h[grow*HD + c8];
    u32 gr[4] = {g4.x,g4.y,g4.z,g4.w};
    u32 hr[4] = {h4.x,h4.y,h4.z,h4.w};
    float v[8];
    #pragma unroll
    for (int j=0;j<4;j++){
        v[2*j]   = lo16(gr[j]) + lo16(hr[j]);
        v[2*j+1] = hi16(gr[j]) + hi16(hr[j]);
    }
    float s = 0.f;
    #pragma unroll
    for (int k=0;k<8;k++) s += v[k];
    #pragma unroll
    for (int msk=1; msk<32; msk<<=1) s += __shfl_xor(s, msk, 32);
    float mean = s * (1.f/256.f);
    float vv = 0.f;
    #pragma unroll
    for (int k=0;k<8;k++){ float d = v[k]-mean; vv += d*d; }
    #pragma unroll
    for (int msk=1; msk<32; msk<<=1) vv += __shfl_xor(vv, msk, 32);
    float inv = rsqrtf(vv*(1.f/256.f) + EPSV);
    float4 g0 = *(const float4*)&gam[c8];
    float4 g1 = *(const float4*)&gam[c8+4];
    float4 b0 = *(const float4*)&bet[c8];
    float4 b1 = *(const float4*)&bet[c8+4];
    float gg[8] = {g0.x,g0.y,g0.z,g0.w,g1.x,g1.y,g1.z,g1.w};
    float bb[8] = {b0.x,b0.y,b0.z,b0.w,b1.x,b1.y,b1.z,b1.w};
    u32 out[4];
    #pragma unroll
    for (int j=0;j<4;j++){
        u16 a = f2bf((v[2*j]-mean)*inv*gg[2*j] + bb[2*j]);
        u16 b = f2bf((v[2*j+1]-mean)*inv*gg[2*j+1] + bb[2*j+1]);
        out[j] = (u32)a | ((u32)b << 16);
    }
    uint4 o4 = {out[0], out[1], out[2], out[3]};
    *(uint4*)&h[grow*HD + c8] = o4;
}

// ---------------- mixprop on cls tokens, in-place h (bf16) update ----------------
__global__ __launch_bounds__(256)
void k_mixprop(u16* __restrict__ h, const float* __restrict__ a,
               const float* __restrict__ Wm, const float* __restrict__ bm)
{
    int n = blockIdx.x >> 2, tt = blockIdx.x & 3;
    __shared__ float xs[256][17], h1s[256][17], h2s[256][17];
    __shared__ float as[16][17];
    int t = threadIdx.x;
    as[t>>4][t&15] = a[t];
    for (int idx=t; idx<4096; idx+=256){
        int w = idx >> 8, hc = idx & 255;
        xs[hc][w] = bf2f(h[((size_t)(n*16 + w)*LSEQ + TT + tt)*HD + hc]);
    }
    __syncthreads();
    for (int idx=t; idx<4096; idx+=256){
        int v = idx & 15, hc = idx >> 4;
        float acc = 0.f;
        #pragma unroll
        for (int w=0;w<16;w++) acc += as[v][w]*xs[hc][w];
        h1s[hc][v] = acc;
    }
    __syncthreads();
    for (int idx=t; idx<4096; idx+=256){
        int v = idx & 15, hc = idx >> 4;
        float acc = 0.f;
        #pragma unroll
        for (int w=0;w<16;w++) acc += as[v][w]*h1s[hc][w];
        h2s[hc][v] = acc;
    }
    __syncthreads();
    int o = t;
    const float* wr = Wm + (size_t)o*768;
    float acc[16];
    #pragma unroll
    for (int w=0;w<16;w++) acc[w] = 0.f;
    for (int hc=0; hc<256; hc++){
        float w0 = wr[hc];
        float w1 = wr[256+hc];
        float w2 = wr[512+hc];
        #pragma unroll
        for (int w=0;w<16;w++)
            acc[w] += xs[hc][w]*w0 + h1s[hc][w]*w1 + h2s[hc][w]*w2;
    }
    float bb = bm[o];
    #pragma unroll
    for (int w=0;w<16;w++)
        h[((size_t)(n*16 + w)*LSEQ + TT + tt)*HD + o] = f2bf(acc[w] + bb);
}

// ---------------- head ----------------
__global__ __launch_bounds__(256)
void k_z(const u16* __restrict__ h, u16* __restrict__ z)
{
    int bid = blockIdx.x, t = threadIdx.x;     // bid = n*16+c
    #pragma unroll
    for (int tc=0;tc<4;tc++)
        z[((size_t)bid*4 + tc)*HD + t] = f2bf(tanhf(bf2f(h[((size_t)bid*LSEQ + TT + tc)*HD + t])));
}

// head1 partial: grid (nb 0..15, kb 0..7); C[64 x 16] partial over K-chunk of 2048
__global__ __launch_bounds__(256)
void k_head1p(const u16* __restrict__ z, const u16* __restrict__ Wd1b,
              float* __restrict__ d1p)
{
    __shared__ float zch[64][137];
    __shared__ float wt[16][137];
    int t = threadIdx.x;
    int col = t & 15, rgrp = t >> 4;
    int ob = blockIdx.x * 16;
    int kb = blockIdx.y;
    float acc[4] = {0.f,0.f,0.f,0.f};
    for (int kc=0; kc<2048; kc+=128){
        int base_k = kb*2048 + kc;
        #pragma unroll
        for (int jj=0; jj<16; jj++){
            int idx = t + jj*256;              // 4096 u32 slots
            int n = idx >> 6, k2 = (idx & 63) << 1;
            u32 r = *(const u32*)&z[(size_t)n*16384 + base_k + k2];
            zch[n][k2] = lo16(r); zch[n][k2+1] = hi16(r);
        }
        #pragma unroll
        for (int jj=0; jj<4; jj++){
            int idx = t + jj*256;              // 1024 u32 slots
            int r = idx >> 6, k2 = (idx & 63) << 1;
            u32 w = *(const u32*)&Wd1b[(size_t)(ob + r)*16384 + base_k + k2];
            wt[r][k2] = lo16(w); wt[r][k2+1] = hi16(w);
        }
        __syncthreads();
        for (int k=0;k<128;k++){
            float wv = wt[col][k];
            #pragma unroll
            for (int u=0;u<4;u++) acc[u] += zch[rgrp + 16*u][k]*wv;
        }
        __syncthreads();
    }
    #pragma unroll
    for (int u=0;u<4;u++)
        d1p[(size_t)(kb*64 + rgrp + 16*u)*HD + ob + col] = acc[u];
}

__global__ __launch_bounds__(256)
void k_head1r(const float* __restrict__ d1p, const float* __restrict__ bd1,
              float* __restrict__ d1)
{
    int e = blockIdx.x*256 + threadIdx.x;      // 16384
    int r = e >> 8, c = e & 255;
    float s = 0.f;
    #pragma unroll
    for (int kb=0; kb<8; kb++) s += d1p[(size_t)(kb*64 + r)*HD + c];
    float xx = s + bd1[c];
    float ge = 0.5f*xx*(1.f + erff(xx*0.70710678118654752f));
    d1[(size_t)r*HD + c] = ge;
}

__global__ __launch_bounds__(64)
void k_head2(const float* __restrict__ d1, const float* __restrict__ Wd2,
             const float* __restrict__ bd2, float* __restrict__ out)
{
    int n = blockIdx.x, lane = threadIdx.x;
    float p = 0.f;
    #pragma unroll
    for (int j=0;j<4;j++){
        int k = lane*4 + j;
        p += d1[(size_t)n*HD + k]*Wd2[k];
    }
    #pragma unroll
    for (int m=1;m<64;m<<=1) p += __shfl_xor(p, m, 64);
    if (lane==0) out[n] = p + bd2[0];
}

// ---------------- launch ----------------
extern "C" void kernel_launch(void* const* d_in, const int* in_sizes, int n_in,
                              void* d_out, int out_size, void* d_ws, size_t ws_size,
                              hipStream_t stream)
{
    const float* x    = (const float*)d_in[0];
    const float* Wfc  = (const float*)d_in[3];
    const float* bfc  = (const float*)d_in[4];
    const float* cls  = (const float*)d_in[5];
    const float* pos  = (const float*)d_in[6];
    const float* emb1 = (const float*)d_in[7];
    const float* emb2 = (const float*)d_in[8];
    const float* Wl1  = (const float*)d_in[9];
    const float* bl1  = (const float*)d_in[10];
    const float* Wl2  = (const float*)d_in[11];
    const float* bl2  = (const float*)d_in[12];
    const float* Wqkv = (const float*)d_in[13];
    const float* bqkv = (const float*)d_in[14];
    const float* Wo   = (const float*)d_in[15];
    const float* bo   = (const float*)d_in[16];
    const float* W1   = (const float*)d_in[17];
    const float* b1   = (const float*)d_in[18];
    const float* W2   = (const float*)d_in[19];
    const float* b2   = (const float*)d_in[20];
    const float* ln1g = (const float*)d_in[21];
    const float* ln1b = (const float*)d_in[22];
    const float* ln2g = (const float*)d_in[23];
    const float* ln2b = (const float*)d_in[24];
    const float* Wmlp = (const float*)d_in[25];
    const float* bmlp = (const float*)d_in[26];
    const float* Wd1  = (const float*)d_in[27];
    const float* bd1  = (const float*)d_in[28];
    const float* Wd2  = (const float*)d_in[29];
    const float* bd2  = (const float*)d_in[30];

    // workspace layout (~98 MB)
    u16* h    = (u16*)d_ws;                    // 26,214,400
    u16* buf  = h    + (size_t)MTOK*HD;        // 13,107,200  (qkv 12800x768 / ff1 12800x1024)
    u16* buf2 = buf  + (size_t)RCH*1024;       //  3,276,800  (12800x256 gemm out)
    u16* wq   = buf2 + (size_t)RCH*256;        //    196,608
    u16* wo   = wq   + 768*256;                //     65,536
    u16* w1   = wo   + 256*256;                //    262,144
    u16* w2   = w1   + 1024*256;               //    262,144
    u16* wd1b = w2   + 256*1024;               //  4,194,304
    u16* zb   = wd1b + (size_t)256*16384;      //  1,048,576
    float* fp = (float*)(zb + (size_t)BSZ*16384);
    float* m1  = fp;                           // 4096
    float* m2  = m1 + CCH*HD;                  // 4096
    float* an  = m2 + CCH*HD;                  // 256
    float* d1p = an + CCH*CCH;                 // 8*64*256 = 131072
    float* d1  = d1p + 8*64*HD;                // 16384

    k_embed<<<MTOK, 256, 0, stream>>>(x, Wfc, bfc, cls, pos, h);
    k_graph_m<<<16, 256, 0, stream>>>(emb1, Wl1, bl1, m1);
    k_graph_m<<<16, 256, 0, stream>>>(emb2, Wl2, bl2, m2);
    k_graph_a<<<1, 256, 0, stream>>>(m1, m2, an);

    for (int l=0; l<NLAY; l++){
        // convert this layer's weights to bf16
        k_cvt<<<512, 256, 0, stream>>>(Wqkv + (size_t)l*768*HD, wq, 768*HD);
        k_cvt<<<256, 256, 0, stream>>>(Wo   + (size_t)l*HD*HD,  wo, HD*HD);
        k_cvt<<<512, 256, 0, stream>>>(W1   + (size_t)l*1024*HD, w1, 1024*HD);
        k_cvt<<<512, 256, 0, stream>>>(W2   + (size_t)l*HD*1024, w2, HD*1024);

        if (l > 0)
            k_mixprop<<<BSZ*NCLS, 256, 0, stream>>>(h, an,
                Wmlp + (size_t)(l-1)*HD*768, bmlp + (size_t)(l-1)*HD);

        for (int c=0; c<NCH; c++){
            size_t row0 = (size_t)c * RCH;
            // qkv projection: (12800x256) @ (768x256)^T -> buf (12800x768)
            k_gemmA<<<dim3(RCH/128, 768/128), 256, 0, stream>>>(
                h + row0*HD, HD, wq, bqkv + (size_t)l*768, buf, 768, HD, 0);
            // attention (writes o into q slot of buf)
            k_attn<<<SCH*NHEAD/2, 256, 0, stream>>>(buf);
            // out-proj: (12800x256[q-slot lda 768]) @ (256x256)^T -> buf2
            k_gemmA<<<dim3(RCH/128, 256/128), 256, 0, stream>>>(
                buf, 768, wo, bo + (size_t)l*HD, buf2, 256, HD, 0);
            k_ln<<<RCH/8, 256, 0, stream>>>(buf2, h,
                ln1g + (size_t)l*HD, ln1b + (size_t)l*HD, row0);
            // FF1: (12800x256) @ (1024x256)^T -> buf, relu
            k_gemmA<<<dim3(RCH/128, 1024/128), 256, 0, stream>>>(
                h + row0*HD, HD, w1, b1 + (size_t)l*1024, buf, 1024, HD, 1);
            // FF2: (12800x1024) @ (256x1024)^T -> buf2
            k_gemmA<<<dim3(RCH/128, 256/128), 256, 0, stream>>>(
                buf, 1024, w2, b2 + (size_t)l*HD, buf2, 256, 1024, 0);
            k_ln<<<RCH/8, 256, 0, stream>>>(buf2, h,
                ln2g + (size_t)l*HD, ln2b + (size_t)l*HD, row0);
        }
    }

    k_z<<<BSZ*CCH, 256, 0, stream>>>(h, zb);
    k_cvt<<<1024, 256, 0, stream>>>(Wd1, wd1b, 256*16384);
    k_head1p<<<dim3(16, 8), 256, 0, stream>>>(zb, wd1b, d1p);
    k_head1r<<<64, 256, 0, stream>>>(d1p, bd1, d1);
    k_head2<<<BSZ, 64, 0, stream>>>(d1, Wd2, bd2, (float*)d_out);
}